// Round 1
// baseline (300.735 us; speedup 1.0000x reference)
//
#include <hip/hip_runtime.h>
#include <hip/hip_bf16.h>

#define N_NODES 40000
#define N_EDGES 640000
#define ETOT    (N_NODES + N_EDGES)   // 680000
#define D_DIM   128
#define HC      256                   // H*C
#define NEG     0.2f
#define NB1     157                   // ceil(40000/256)

static __device__ __forceinline__ float bf2f(unsigned short u) {
    return __uint_as_float(((unsigned)u) << 16);
}
static __device__ __forceinline__ unsigned short f2bf(float f) {
    __hip_bfloat16 b = __float2bfloat16(f);
    unsigned short r;
    __builtin_memcpy(&r, &b, 2);
    return r;
}

// ---------------- CSR build ----------------
__global__ __launch_bounds__(256) void count_k(const int* __restrict__ ei, int* __restrict__ deg) {
    int e = blockIdx.x * 256 + threadIdx.x;
    if (e >= ETOT) return;
    int dd = (e < N_EDGES) ? ei[N_EDGES + e] : (e - N_EDGES);
    atomicAdd(&deg[dd], 1);
}

__global__ __launch_bounds__(256) void scan1_k(const int* __restrict__ deg, int* __restrict__ rowp,
                                               int* __restrict__ bsum) {
    __shared__ int sd[256];
    int t = threadIdx.x;
    int g = blockIdx.x * 256 + t;
    int v = (g < N_NODES) ? deg[g] : 0;
    sd[t] = v;
    __syncthreads();
    for (int off = 1; off < 256; off <<= 1) {
        int xv = (t >= off) ? sd[t - off] : 0;
        __syncthreads();
        sd[t] += xv;
        __syncthreads();
    }
    if (g < N_NODES) rowp[g] = sd[t] - v;     // exclusive within block
    if (t == 255) bsum[blockIdx.x] = sd[255];
}

__global__ __launch_bounds__(256) void scan2_k(const int* __restrict__ bsum, int* __restrict__ boff,
                                               int* __restrict__ rowp) {
    __shared__ int sd[256];
    int t = threadIdx.x;
    int v = (t < NB1) ? bsum[t] : 0;
    sd[t] = v;
    __syncthreads();
    for (int off = 1; off < 256; off <<= 1) {
        int xv = (t >= off) ? sd[t - off] : 0;
        __syncthreads();
        sd[t] += xv;
        __syncthreads();
    }
    if (t < NB1) boff[t] = sd[t] - v;         // exclusive block offsets
    if (t == 255) rowp[N_NODES] = sd[255];    // total = ETOT
}

__global__ __launch_bounds__(256) void scan3_k(int* __restrict__ rowp, const int* __restrict__ boff,
                                               int* __restrict__ cnt) {
    int g = blockIdx.x * 256 + threadIdx.x;
    if (g < N_NODES) {
        int v = rowp[g] + boff[blockIdx.x];
        rowp[g] = v;
        cnt[g] = v;   // running fill cursor starts at row begin
    }
}

__global__ __launch_bounds__(256) void fill_k(const int* __restrict__ ei, int* __restrict__ cnt,
                                              int* __restrict__ csrc) {
    int e = blockIdx.x * 256 + threadIdx.x;
    if (e >= ETOT) return;
    int ss, dd;
    if (e < N_EDGES) { ss = ei[e]; dd = ei[N_EDGES + e]; }
    else             { ss = e - N_EDGES; dd = ss; }
    int pos = atomicAdd(&cnt[dd], 1);
    csrc[pos] = ss;
}

// ---------------- copy x to output slot 0 ----------------
__global__ __launch_bounds__(256) void copy_k(const float4* __restrict__ src, float4* __restrict__ dst, int n4) {
    int i = blockIdx.x * 256 + threadIdx.x;
    if (i < n4) dst[i] = src[i];
}

// ---------------- GEMM: h[n][o] = sum_k x[n][k] * W[o][k], store bf16 ----------------
// block tile: 64 nodes x 64 channels, 256 threads, 4x4 per-thread tile, K-chunks of 16
__global__ __launch_bounds__(256) void gemm_k(const float* __restrict__ x, const float* __restrict__ W,
                                              unsigned short* __restrict__ h) {
    __shared__ float xs[16][68];   // xs[k][n], padded
    __shared__ float wsd[16][68];  // wsd[k][o], padded
    const int t = threadIdx.x;
    const int bn = (blockIdx.x % 625) * 64;
    const int bo = (blockIdx.x / 625) * 64;
    const int ln = (t & 15) * 4;   // node offset in tile
    const int lo = (t >> 4) * 4;   // channel offset in tile
    const int rowA = t >> 2;       // 0..63
    const int qa = (t & 3) * 4;    // 0,4,8,12
    float acc[4][4] = {};
    for (int k0 = 0; k0 < 128; k0 += 16) {
        float4 xv = *(const float4*)(x + (size_t)(bn + rowA) * 128 + k0 + qa);
        float4 wv = *(const float4*)(W + (size_t)(bo + rowA) * 128 + k0 + qa);
        __syncthreads();
        xs[qa + 0][rowA] = xv.x; xs[qa + 1][rowA] = xv.y; xs[qa + 2][rowA] = xv.z; xs[qa + 3][rowA] = xv.w;
        wsd[qa + 0][rowA] = wv.x; wsd[qa + 1][rowA] = wv.y; wsd[qa + 2][rowA] = wv.z; wsd[qa + 3][rowA] = wv.w;
        __syncthreads();
#pragma unroll
        for (int k = 0; k < 16; k++) {
            float4 a = *(const float4*)&xs[k][ln];
            float4 b = *(const float4*)&wsd[k][lo];
            acc[0][0] += a.x * b.x; acc[0][1] += a.x * b.y; acc[0][2] += a.x * b.z; acc[0][3] += a.x * b.w;
            acc[1][0] += a.y * b.x; acc[1][1] += a.y * b.y; acc[1][2] += a.y * b.z; acc[1][3] += a.y * b.w;
            acc[2][0] += a.z * b.x; acc[2][1] += a.z * b.y; acc[2][2] += a.z * b.z; acc[2][3] += a.z * b.w;
            acc[3][0] += a.w * b.x; acc[3][1] += a.w * b.y; acc[3][2] += a.w * b.z; acc[3][3] += a.w * b.w;
        }
    }
#pragma unroll
    for (int i = 0; i < 4; i++) {
        ushort4 us;
        us.x = f2bf(acc[i][0]); us.y = f2bf(acc[i][1]); us.z = f2bf(acc[i][2]); us.w = f2bf(acc[i][3]);
        *(ushort4*)(h + (size_t)(bn + ln + i) * HC + bo + lo) = us;
    }
}

// ---------------- per-node attention logits ----------------
// wave per node; lane covers 4 channels of flattened 256; head = lane>=32
__global__ __launch_bounds__(256) void enode_k(const unsigned short* __restrict__ h,
                                               const float* __restrict__ a_s, const float* __restrict__ a_d,
                                               float2* __restrict__ esrc, float2* __restrict__ edst) {
    const int lane = threadIdx.x & 63;
    const int wid = threadIdx.x >> 6;
    const int n = blockIdx.x * 4 + wid;
    if (n >= N_NODES) return;
    const int head = lane >> 5;
    const int ch = (lane & 31) * 4;     // within-head channel
    float4 av = *(const float4*)(a_s + head * 128 + ch);
    float4 dv = *(const float4*)(a_d + head * 128 + ch);
    ushort4 hv = *(const ushort4*)(h + (size_t)n * HC + lane * 4);
    float4 hf = { bf2f(hv.x), bf2f(hv.y), bf2f(hv.z), bf2f(hv.w) };
    float ps = hf.x * av.x + hf.y * av.y + hf.z * av.z + hf.w * av.w;
    float pd = hf.x * dv.x + hf.y * dv.y + hf.z * dv.z + hf.w * dv.w;
#pragma unroll
    for (int m = 1; m < 32; m <<= 1) {
        ps += __shfl_xor(ps, m, 64);
        pd += __shfl_xor(pd, m, 64);
    }
    float ps1 = __shfl(ps, 32, 64);
    float pd1 = __shfl(pd, 32, 64);
    if (lane == 0) {
        esrc[n] = make_float2(ps, ps1);
        edst[n] = make_float2(pd, pd1);
    }
}

// ---------------- per-dst softmax + aggregation ----------------
// wave per dst node; no segment-max (shift-invariant softmax, exp clamped); no atomics.
__global__ __launch_bounds__(256) void agg_k(const unsigned short* __restrict__ h,
                                             const float2* __restrict__ esrc, const float2* __restrict__ edst,
                                             const int* __restrict__ rowp, const int* __restrict__ csrc,
                                             const float* __restrict__ bias, float* __restrict__ out) {
    const int lane = threadIdx.x & 63;
    const int wid = threadIdx.x >> 6;
    const int d = blockIdx.x * 4 + wid;
    if (d >= N_NODES) return;
    const int r0 = rowp[d];
    const int deg = rowp[d + 1] - r0;
    const float2 ed = edst[d];
    const int head = lane >> 5;
    float4 acc = { 0.f, 0.f, 0.f, 0.f };
    float ssum = 0.f;
    for (int base = 0; base < deg; base += 64) {
        int cnt = min(64, deg - base);
        int s = 0;
        float p0 = 0.f, p1 = 0.f;
        if (lane < cnt) {
            s = csrc[r0 + base + lane];
            float2 es = esrc[s];
            float e0 = es.x + ed.x; e0 = e0 > 0.f ? e0 : NEG * e0;
            float e1 = es.y + ed.y; e1 = e1 > 0.f ? e1 : NEG * e1;
            p0 = __expf(fminf(e0, 60.f));
            p1 = __expf(fminf(e1, 60.f));
        }
        for (int j = 0; j < cnt; j++) {
            int sj = __shfl(s, j, 64);
            float q0 = __shfl(p0, j, 64);
            float q1 = __shfl(p1, j, 64);
            float p = head ? q1 : q0;
            ushort4 hv = *(const ushort4*)(h + (size_t)sj * HC + lane * 4);
            acc.x += p * bf2f(hv.x);
            acc.y += p * bf2f(hv.y);
            acc.z += p * bf2f(hv.z);
            acc.w += p * bf2f(hv.w);
            ssum += p;
        }
    }
    float inv = 1.f / ssum;
    acc.x *= inv; acc.y *= inv; acc.z *= inv; acc.w *= inv;
    // combine heads: lane l and l^32 hold same within-head channels for head0/head1
    float4 o;
    o.x = (acc.x + __shfl_xor(acc.x, 32, 64)) * 0.5f;
    o.y = (acc.y + __shfl_xor(acc.y, 32, 64)) * 0.5f;
    o.z = (acc.z + __shfl_xor(acc.z, 32, 64)) * 0.5f;
    o.w = (acc.w + __shfl_xor(acc.w, 32, 64)) * 0.5f;
    const int cc = (lane & 31) * 4;
    float4 bv = *(const float4*)(bias + cc);
    o.x += bv.x; o.y += bv.y; o.z += bv.z; o.w += bv.w;
    o.x = o.x > 0.f ? o.x : (__expf(o.x) - 1.f);
    o.y = o.y > 0.f ? o.y : (__expf(o.y) - 1.f);
    o.z = o.z > 0.f ? o.z : (__expf(o.z) - 1.f);
    o.w = o.w > 0.f ? o.w : (__expf(o.w) - 1.f);
    if (lane < 32) *(float4*)(out + (size_t)d * D_DIM + cc) = o;
}

extern "C" void kernel_launch(void* const* d_in, const int* in_sizes, int n_in,
                              void* d_out, int out_size, void* d_ws, size_t ws_size,
                              hipStream_t stream) {
    const float* x  = (const float*)d_in[0];
    const int* ei   = (const int*)d_in[1];
    const float* W  = (const float*)d_in[2];
    const float* as_ = (const float*)d_in[3];
    const float* ad_ = (const float*)d_in[4];
    const float* bias = (const float*)d_in[5];
    float* out = (float*)d_out;

    char* ws = (char*)d_ws;
    size_t off = 0;
    auto alloc = [&](size_t bytes) -> void* {
        void* p = ws + off;
        off = (off + bytes + 255) & ~(size_t)255;
        return p;
    };
    unsigned short* hbf = (unsigned short*)alloc((size_t)N_NODES * HC * 2);  // 20.48 MB
    float2* esrc = (float2*)alloc((size_t)N_NODES * 8);
    float2* edst = (float2*)alloc((size_t)N_NODES * 8);
    int* deg  = (int*)alloc((size_t)N_NODES * 4);
    int* rowp = (int*)alloc((size_t)(N_NODES + 1) * 4);
    int* cnt  = (int*)alloc((size_t)N_NODES * 4);
    int* bsum = (int*)alloc((size_t)NB1 * 4);
    int* boff = (int*)alloc((size_t)NB1 * 4);
    int* csrc = (int*)alloc((size_t)ETOT * 4);

    // CSR build
    hipMemsetAsync(deg, 0, (size_t)N_NODES * 4, stream);
    count_k<<<(ETOT + 255) / 256, 256, 0, stream>>>(ei, deg);
    scan1_k<<<NB1, 256, 0, stream>>>(deg, rowp, bsum);
    scan2_k<<<1, 256, 0, stream>>>(bsum, boff, rowp);
    scan3_k<<<NB1, 256, 0, stream>>>(rowp, boff, cnt);
    fill_k<<<(ETOT + 255) / 256, 256, 0, stream>>>(ei, cnt, csrc);

    // output slot 0 = x
    copy_k<<<(N_NODES * D_DIM / 4 + 255) / 256, 256, 0, stream>>>((const float4*)x, (float4*)out,
                                                                  N_NODES * D_DIM / 4);

    const size_t nd = (size_t)N_NODES * D_DIM;
    for (int l = 0; l < 2; l++) {
        const float* xl = (l == 0) ? x : (out + (size_t)l * nd);
        float* ol = out + (size_t)(l + 1) * nd;
        gemm_k<<<2500, 256, 0, stream>>>(xl, W + (size_t)l * HC * D_DIM, hbf);
        enode_k<<<(N_NODES + 3) / 4, 256, 0, stream>>>(hbf, as_ + l * HC, ad_ + l * HC, esrc, edst);
        agg_k<<<(N_NODES + 3) / 4, 256, 0, stream>>>(hbf, esrc, edst, rowp, csrc, bias + l * D_DIM, ol);
    }
}